// Round 6
// baseline (383.106 us; speedup 1.0000x reference)
//
#include <hip/hip_runtime.h>

#define N_NODES 50000
#define N_EDGES 800000
static constexpr float EPS = 1e-5f;
static constexpr int SCAN_NB = (N_NODES + 255) / 256;   // 196

using bf16x8 = __attribute__((ext_vector_type(8))) short;  // 8 bf16 (4 VGPRs)
using f32x4  = __attribute__((ext_vector_type(4))) float;

// ---- bf16 helpers (raw-bit, RNE) ----
static __device__ __forceinline__ unsigned short f2bf(float f) {
    unsigned int u = __float_as_uint(f);
    return (unsigned short)((u + 0x7FFFu + ((u >> 16) & 1u)) >> 16);
}
static __device__ __forceinline__ float blo(unsigned int w) { return __uint_as_float(w << 16); }
static __device__ __forceinline__ float bhi(unsigned int w) { return __uint_as_float(w & 0xffff0000u); }

// ---------------------------------------------------------------------------
// prep: in-degree histogram
// ---------------------------------------------------------------------------
__global__ __launch_bounds__(256) void k_prep(const int* __restrict__ ei,
                                              int* __restrict__ deg) {
    int e = blockIdx.x * 256 + threadIdx.x;
    if (e >= N_EDGES) return;
    atomicAdd(&deg[ei[N_EDGES + e]], 1);
}

__global__ __launch_bounds__(256) void k_inv(const int* __restrict__ deg,
                                             float* __restrict__ inv_sqrt) {
    int i = blockIdx.x * 256 + threadIdx.x;
    if (i >= N_NODES) return;
    inv_sqrt[i] = rsqrtf((float)deg[i] + 1.0f);
}

// ---------------------------------------------------------------------------
// hierarchical exclusive scan: deg[N] -> rowptr[N+1] (+cursor copy)
// ---------------------------------------------------------------------------
__global__ __launch_bounds__(256) void k_scan1(const int* __restrict__ deg,
                                               int* __restrict__ excl,
                                               int* __restrict__ partials) {
    const int t = threadIdx.x;
    const int i = blockIdx.x * 256 + t;
    int v = (i < N_NODES) ? deg[i] : 0;
    __shared__ int sh[256];
    sh[t] = v;
    __syncthreads();
    for (int off = 1; off < 256; off <<= 1) {
        int u = (t >= off) ? sh[t - off] : 0;
        __syncthreads();
        sh[t] += u;
        __syncthreads();
    }
    if (i < N_NODES) excl[i] = sh[t] - v;
    if (t == 255) partials[blockIdx.x] = sh[t];
}

__global__ __launch_bounds__(256) void k_scan2(int* __restrict__ partials) {
    const int t = threadIdx.x;
    int v = (t < SCAN_NB) ? partials[t] : 0;
    __shared__ int sh[256];
    sh[t] = v;
    __syncthreads();
    for (int off = 1; off < 256; off <<= 1) {
        int u = (t >= off) ? sh[t - off] : 0;
        __syncthreads();
        sh[t] += u;
        __syncthreads();
    }
    if (t < SCAN_NB) partials[t] = sh[t] - v;
}

__global__ __launch_bounds__(256) void k_scan3(const int* __restrict__ excl,
                                               const int* __restrict__ partials,
                                               int* __restrict__ rowptr,
                                               int* __restrict__ cursor) {
    const int i = blockIdx.x * 256 + threadIdx.x;
    if (i < N_NODES) {
        int r = excl[i] + partials[blockIdx.x];
        rowptr[i] = r;
        cursor[i] = r;
    }
    if (i == 0) rowptr[N_NODES] = N_EDGES;
}

// ---------------------------------------------------------------------------
// fill CSR buckets: one 4B store per edge (src only; coef computed in k_agg)
// ---------------------------------------------------------------------------
__global__ __launch_bounds__(256) void k_fill(const int* __restrict__ ei,
                                              int* __restrict__ cursor,
                                              int* __restrict__ esrc) {
    int e = blockIdx.x * 256 + threadIdx.x;
    if (e >= N_EDGES) return;
    int s = ei[e];
    int d = ei[N_EDGES + e];
    int pos = atomicAdd(&cursor[d], 1);
    esrc[pos] = s;
}

// ---------------------------------------------------------------------------
// W fp32 [128][NCOL] -> bf16 packed in B-fragment order
// ---------------------------------------------------------------------------
template <int NCOL>
__global__ __launch_bounds__(256) void k_wconv(const float* __restrict__ W,
                                               unsigned short* __restrict__ Wf) {
    int idx = blockIdx.x * 256 + threadIdx.x;
    if (idx >= NCOL * 128) return;
    int j  = idx & 7;
    int l  = (idx >> 3) & 63;
    int s  = (idx >> 9) & 3;
    int tn = idx >> 11;
    int n = tn * 16 + (l & 15);
    int k = s * 32 + (l >> 4) * 8 + j;
    Wf[idx] = f2bf(W[k * NCOL + n]);
}

// ---------------------------------------------------------------------------
// MFMA GEMM: H(bf16) = act(A) @ W, act = BN+ReLU if BN.
// ---------------------------------------------------------------------------
template <int NCOL, bool BN, bool ABF16>
__global__ __launch_bounds__(256) void k_gemm(
    const void* __restrict__ Ap, const unsigned short* __restrict__ Wf,
    const float* __restrict__ stats,
    const float* __restrict__ gamma, const float* __restrict__ beta,
    unsigned short* __restrict__ H) {
    const int t = threadIdx.x;
    const int row0 = blockIdx.x * 64;

    __shared__ unsigned short As[64 * 136];   // bf16, row stride 136 (+8 pad)
    __shared__ float sc_s[128], sh_s[128];

    if (BN) {
        if (t < 128) {
            float s  = stats[t];
            float sq = stats[128 + t];
            float mean = s * (1.0f / N_NODES);
            float var  = sq * (1.0f / N_NODES) - mean * mean;
            float sc = gamma[t] * rsqrtf(var + EPS);
            sc_s[t] = sc;
            sh_s[t] = beta[t] - mean * sc;
        }
        __syncthreads();
    }

    // ---- stage 64x128 A-tile into LDS as bf16 (BN+ReLU fused, fp32 math) ----
#pragma unroll
    for (int i = 0; i < 4; i++) {
        int q = i * 256 + t;
        int row = q >> 4;
        int c8  = (q & 15) * 8;
        int grow = row0 + row;
        float v[8];
        if (grow < N_NODES) {
            if (ABF16) {
                uint4 p = *(const uint4*)((const unsigned short*)Ap + (size_t)grow * 128 + c8);
                v[0] = blo(p.x); v[1] = bhi(p.x); v[2] = blo(p.y); v[3] = bhi(p.y);
                v[4] = blo(p.z); v[5] = bhi(p.z); v[6] = blo(p.w); v[7] = bhi(p.w);
            } else {
                const float* Af = (const float*)Ap + (size_t)grow * 128 + c8;
                float4 f0 = *(const float4*)Af;
                float4 f1 = *(const float4*)(Af + 4);
                v[0] = f0.x; v[1] = f0.y; v[2] = f0.z; v[3] = f0.w;
                v[4] = f1.x; v[5] = f1.y; v[6] = f1.z; v[7] = f1.w;
            }
        } else {
#pragma unroll
            for (int j = 0; j < 8; j++) v[j] = 0.f;
        }
        if (BN) {
#pragma unroll
            for (int j = 0; j < 8; j++)
                v[j] = fmaxf(fmaf(v[j], sc_s[c8 + j], sh_s[c8 + j]), 0.f);
        }
        uint4 pk;
        pk.x = (unsigned)f2bf(v[0]) | ((unsigned)f2bf(v[1]) << 16);
        pk.y = (unsigned)f2bf(v[2]) | ((unsigned)f2bf(v[3]) << 16);
        pk.z = (unsigned)f2bf(v[4]) | ((unsigned)f2bf(v[5]) << 16);
        pk.w = (unsigned)f2bf(v[6]) | ((unsigned)f2bf(v[7]) << 16);
        *(uint4*)&As[row * 136 + c8] = pk;
    }
    __syncthreads();

    // ---- fragments & MFMA ----
    const int wv = t >> 6;
    const int l  = t & 63;
    const int m  = l & 15;
    const int kq = l >> 4;

    bf16x8 afrag[4];
    const unsigned short* arow = &As[(wv * 16 + m) * 136 + kq * 8];
#pragma unroll
    for (int s = 0; s < 4; s++)
        afrag[s] = *(const bf16x8*)(arow + s * 32);

    constexpr int NT = NCOL / 16;
#pragma unroll
    for (int tn = 0; tn < NT; tn++) {
        f32x4 acc = {0.f, 0.f, 0.f, 0.f};
#pragma unroll
        for (int s = 0; s < 4; s++) {
            bf16x8 b = *(const bf16x8*)&Wf[(size_t)((tn * 4 + s) * 64 + l) * 8];
            acc = __builtin_amdgcn_mfma_f32_16x16x32_bf16(afrag[s], b, acc, 0, 0, 0);
        }
        int col = tn * 16 + m;
#pragma unroll
        for (int r = 0; r < 4; r++) {
            int row = row0 + wv * 16 + kq * 4 + r;
            if (row < N_NODES) H[(size_t)row * NCOL + col] = f2bf(acc[r]);
        }
    }
}

// ---------------------------------------------------------------------------
// CSR gather-aggregate from bf16 H, fp32 accumulate, 4-wide unroll.
// coef computed on the fly: inv_sqrt[s] * inv_sqrt[node] (L2-resident gathers)
// ---------------------------------------------------------------------------
template <int F, bool OUTBF>
__global__ __launch_bounds__(256) void k_agg(const int* __restrict__ rowptr,
                                             const int* __restrict__ esrc,
                                             const float* __restrict__ inv_sqrt,
                                             const unsigned short* __restrict__ H,
                                             const float* __restrict__ bias,
                                             void* __restrict__ OUT) {
    constexpr int LPN = F / 4;              // lanes per node (32 or 16)
    constexpr int NPB = 256 / LPN;
    const int t = threadIdx.x;
    const int node = blockIdx.x * NPB + t / LPN;
    const int lane = t % LPN;
    if (node >= N_NODES) return;

    const uint2* __restrict__ Hv = (const uint2*)H;   // 4 bf16 per uint2
    const int beg = rowptr[node];
    const int end = rowptr[node + 1];
    const float rsn = inv_sqrt[node];

    float4 acc = make_float4(0.f, 0.f, 0.f, 0.f);
    int j = beg;
    for (; j + 3 < end; j += 4) {
        int s0 = esrc[j], s1 = esrc[j + 1], s2 = esrc[j + 2], s3 = esrc[j + 3];
        uint2 p0 = Hv[(size_t)s0 * LPN + lane];
        uint2 p1 = Hv[(size_t)s1 * LPN + lane];
        uint2 p2 = Hv[(size_t)s2 * LPN + lane];
        uint2 p3 = Hv[(size_t)s3 * LPN + lane];
        float c0 = inv_sqrt[s0] * rsn, c1 = inv_sqrt[s1] * rsn;
        float c2 = inv_sqrt[s2] * rsn, c3 = inv_sqrt[s3] * rsn;
        acc.x = fmaf(blo(p0.x), c0, acc.x); acc.y = fmaf(bhi(p0.x), c0, acc.y);
        acc.z = fmaf(blo(p0.y), c0, acc.z); acc.w = fmaf(bhi(p0.y), c0, acc.w);
        acc.x = fmaf(blo(p1.x), c1, acc.x); acc.y = fmaf(bhi(p1.x), c1, acc.y);
        acc.z = fmaf(blo(p1.y), c1, acc.z); acc.w = fmaf(bhi(p1.y), c1, acc.w);
        acc.x = fmaf(blo(p2.x), c2, acc.x); acc.y = fmaf(bhi(p2.x), c2, acc.y);
        acc.z = fmaf(blo(p2.y), c2, acc.z); acc.w = fmaf(bhi(p2.y), c2, acc.w);
        acc.x = fmaf(blo(p3.x), c3, acc.x); acc.y = fmaf(bhi(p3.x), c3, acc.y);
        acc.z = fmaf(blo(p3.y), c3, acc.z); acc.w = fmaf(bhi(p3.y), c3, acc.w);
    }
    for (; j < end; j++) {
        int s0 = esrc[j];
        float c0 = inv_sqrt[s0] * rsn;
        uint2 p0 = Hv[(size_t)s0 * LPN + lane];
        acc.x = fmaf(blo(p0.x), c0, acc.x); acc.y = fmaf(bhi(p0.x), c0, acc.y);
        acc.z = fmaf(blo(p0.y), c0, acc.z); acc.w = fmaf(bhi(p0.y), c0, acc.w);
    }

    // self-loop + bias (self coef = rsn^2)
    uint2 ps = Hv[(size_t)node * LPN + lane];
    float idv = rsn * rsn;
    float4 b4 = ((const float4*)bias)[lane];
    acc.x = fmaf(blo(ps.x), idv, acc.x) + b4.x;
    acc.y = fmaf(bhi(ps.x), idv, acc.y) + b4.y;
    acc.z = fmaf(blo(ps.y), idv, acc.z) + b4.z;
    acc.w = fmaf(bhi(ps.y), idv, acc.w) + b4.w;

    if (OUTBF) {
        uint2 pk;
        pk.x = (unsigned)f2bf(acc.x) | ((unsigned)f2bf(acc.y) << 16);
        pk.y = (unsigned)f2bf(acc.z) | ((unsigned)f2bf(acc.w) << 16);
        ((uint2*)OUT)[(size_t)node * LPN + lane] = pk;
    } else {
        ((float4*)OUT)[(size_t)node * LPN + lane] = acc;
    }
}

// ---------------------------------------------------------------------------
// column stats over bf16 A[N,128]
// ---------------------------------------------------------------------------
__global__ __launch_bounds__(256) void k_stats(const unsigned short* __restrict__ A,
                                               float* __restrict__ stats) {
    const int t  = threadIdx.x;
    const int c4 = t & 31;
    const int rr = t >> 5;
    float4 sum = make_float4(0.f, 0.f, 0.f, 0.f);
    float4 sq  = make_float4(0.f, 0.f, 0.f, 0.f);
    for (int row = blockIdx.x * 8 + rr; row < N_NODES; row += gridDim.x * 8) {
        uint2 p = *(const uint2*)&A[(size_t)row * 128 + c4 * 4];
        float vx = blo(p.x), vy = bhi(p.x), vz = blo(p.y), vw = bhi(p.y);
        sum.x += vx; sum.y += vy; sum.z += vz; sum.w += vw;
        sq.x += vx * vx; sq.y += vy * vy; sq.z += vz * vz; sq.w += vw * vw;
    }
    __shared__ float4 red[2][8][32];
    red[0][rr][c4] = sum;
    red[1][rr][c4] = sq;
    __syncthreads();
    if (t < 32) {
        float4 s = make_float4(0.f, 0.f, 0.f, 0.f);
        float4 q = make_float4(0.f, 0.f, 0.f, 0.f);
#pragma unroll
        for (int i = 0; i < 8; i++) {
            float4 a = red[0][i][t];
            float4 b = red[1][i][t];
            s.x += a.x; s.y += a.y; s.z += a.z; s.w += a.w;
            q.x += b.x; q.y += b.y; q.z += b.z; q.w += b.w;
        }
        int c = t * 4;
        atomicAdd(&stats[c + 0], s.x); atomicAdd(&stats[c + 1], s.y);
        atomicAdd(&stats[c + 2], s.z); atomicAdd(&stats[c + 3], s.w);
        atomicAdd(&stats[128 + c + 0], q.x); atomicAdd(&stats[128 + c + 1], q.y);
        atomicAdd(&stats[128 + c + 2], q.z); atomicAdd(&stats[128 + c + 3], q.w);
    }
}

// ---------------------------------------------------------------------------
extern "C" void kernel_launch(void* const* d_in, const int* in_sizes, int n_in,
                              void* d_out, int out_size, void* d_ws, size_t ws_size,
                              hipStream_t stream) {
    const float* x   = (const float*)d_in[0];
    const int*   ei  = (const int*)d_in[1];
    const float* W1  = (const float*)d_in[2];
    const float* b1  = (const float*)d_in[3];
    const float* g1  = (const float*)d_in[4];
    const float* bt1 = (const float*)d_in[5];
    const float* W2  = (const float*)d_in[6];
    const float* b2  = (const float*)d_in[7];
    const float* g2  = (const float*)d_in[8];
    const float* bt2 = (const float*)d_in[9];
    const float* W3  = (const float*)d_in[10];
    const float* b3  = (const float*)d_in[11];
    float* out = (float*)d_out;                 // [N, 64] fp32

    char* ws = (char*)d_ws;
    size_t off = 0;
    auto alloc = [&](size_t bytes) { char* p = ws + off; off += (bytes + 255) & ~(size_t)255; return p; };
    int*   deg      = (int*)  alloc((size_t)N_NODES * 4);
    float* inv_sqrt = (float*)alloc((size_t)N_NODES * 4);
    int*   excl     = (int*)  alloc((size_t)N_NODES * 4);
    int*   partials = (int*)  alloc(256 * 4);
    int*   rowptr   = (int*)  alloc((size_t)(N_NODES + 1) * 4);
    int*   cursor   = (int*)  alloc((size_t)N_NODES * 4);
    int*   esrc     = (int*)  alloc((size_t)N_EDGES * 4);
    float* stats1   = (float*)alloc(256 * 4);
    float* stats2   = (float*)alloc(256 * 4);
    unsigned short* Wf1 = (unsigned short*)alloc((size_t)128 * 128 * 2);
    unsigned short* Wf2 = (unsigned short*)alloc((size_t)128 * 128 * 2);
    unsigned short* Wf3 = (unsigned short*)alloc((size_t)64 * 128 * 2);
    unsigned short* h1  = (unsigned short*)alloc((size_t)N_NODES * 128 * 2);
    unsigned short* h2  = (unsigned short*)alloc((size_t)N_NODES * 128 * 2);
    unsigned short* h3  = (unsigned short*)alloc((size_t)N_NODES * 64 * 2);
    unsigned short* agg1 = (unsigned short*)alloc((size_t)N_NODES * 128 * 2);
    unsigned short* agg2 = (unsigned short*)alloc((size_t)N_NODES * 128 * 2);

    hipMemsetAsync(deg, 0, (size_t)N_NODES * 4, stream);
    hipMemsetAsync(stats1, 0, 256 * 4, stream);
    hipMemsetAsync(stats2, 0, 256 * 4, stream);

    k_prep<<<(N_EDGES + 255) / 256, 256, 0, stream>>>(ei, deg);
    k_inv<<<(N_NODES + 255) / 256, 256, 0, stream>>>(deg, inv_sqrt);
    k_scan1<<<SCAN_NB, 256, 0, stream>>>(deg, excl, partials);
    k_scan2<<<1, 256, 0, stream>>>(partials);
    k_scan3<<<SCAN_NB, 256, 0, stream>>>(excl, partials, rowptr, cursor);
    k_fill<<<(N_EDGES + 255) / 256, 256, 0, stream>>>(ei, cursor, esrc);

    k_wconv<128><<<64, 256, 0, stream>>>(W1, Wf1);
    k_wconv<128><<<64, 256, 0, stream>>>(W2, Wf2);
    k_wconv<64><<<32, 256, 0, stream>>>(W3, Wf3);

    const int gemm_grid = (N_NODES + 63) / 64;

    // layer 1
    k_gemm<128, false, false><<<gemm_grid, 256, 0, stream>>>(x, Wf1, nullptr, nullptr, nullptr, h1);
    k_agg<128, true><<<(N_NODES + 7) / 8, 256, 0, stream>>>(rowptr, esrc, inv_sqrt, h1, b1, agg1);
    k_stats<<<256, 256, 0, stream>>>(agg1, stats1);

    // layer 2
    k_gemm<128, true, true><<<gemm_grid, 256, 0, stream>>>(agg1, Wf2, stats1, g1, bt1, h2);
    k_agg<128, true><<<(N_NODES + 7) / 8, 256, 0, stream>>>(rowptr, esrc, inv_sqrt, h2, b2, agg2);
    k_stats<<<256, 256, 0, stream>>>(agg2, stats2);

    // layer 3 (aggregate straight into d_out, fp32)
    k_gemm<64, true, true><<<gemm_grid, 256, 0, stream>>>(agg2, Wf3, stats2, g2, bt2, h3);
    k_agg<64, false><<<(N_NODES + 15) / 16, 256, 0, stream>>>(rowptr, esrc, inv_sqrt, h3, b3, out);
}

// Round 7
// 338.534 us; speedup vs baseline: 1.1317x; 1.1317x over previous
//
#include <hip/hip_runtime.h>

#define N_NODES 50000
#define N_EDGES 800000
static constexpr float EPS = 1e-5f;
static constexpr int SCAN_NB = (N_NODES + 255) / 256;   // 196
static constexpr int GEMM_NB = (N_NODES + 63) / 64;     // 782
static constexpr int FILL_NB = (N_EDGES + 1023) / 1024; // 782 (4 edges/thread)

using bf16x8 = __attribute__((ext_vector_type(8))) short;  // 8 bf16 (4 VGPRs)
using f32x4  = __attribute__((ext_vector_type(4))) float;

// ---- bf16 helpers (raw-bit, RNE) ----
static __device__ __forceinline__ unsigned short f2bf(float f) {
    unsigned int u = __float_as_uint(f);
    return (unsigned short)((u + 0x7FFFu + ((u >> 16) & 1u)) >> 16);
}
static __device__ __forceinline__ float blo(unsigned int w) { return __uint_as_float(w << 16); }
static __device__ __forceinline__ float bhi(unsigned int w) { return __uint_as_float(w & 0xffff0000u); }

// ---------------------------------------------------------------------------
// prep: in-degree histogram + per-edge rank (atomic return value, 4 edges/thr)
// ---------------------------------------------------------------------------
__global__ __launch_bounds__(256) void k_prep(const int* __restrict__ ei,
                                              int* __restrict__ deg,
                                              int* __restrict__ rank) {
    int e0 = (blockIdx.x * 256 + threadIdx.x) * 4;
    if (e0 >= N_EDGES) return;          // N_EDGES % 4 == 0
    int4 d4 = *(const int4*)&ei[N_EDGES + e0];
    int4 r;
    r.x = atomicAdd(&deg[d4.x], 1);
    r.y = atomicAdd(&deg[d4.y], 1);
    r.z = atomicAdd(&deg[d4.z], 1);
    r.w = atomicAdd(&deg[d4.w], 1);
    *(int4*)&rank[e0] = r;
}

// ---------------------------------------------------------------------------
// hierarchical exclusive scan: deg[N] -> rowptr[N+1]; stage 3 also does inv_sqrt
// ---------------------------------------------------------------------------
__global__ __launch_bounds__(256) void k_scan1(const int* __restrict__ deg,
                                               int* __restrict__ excl,
                                               int* __restrict__ partials) {
    const int t = threadIdx.x;
    const int i = blockIdx.x * 256 + t;
    int v = (i < N_NODES) ? deg[i] : 0;
    __shared__ int sh[256];
    sh[t] = v;
    __syncthreads();
    for (int off = 1; off < 256; off <<= 1) {
        int u = (t >= off) ? sh[t - off] : 0;
        __syncthreads();
        sh[t] += u;
        __syncthreads();
    }
    if (i < N_NODES) excl[i] = sh[t] - v;
    if (t == 255) partials[blockIdx.x] = sh[t];
}

__global__ __launch_bounds__(256) void k_scan2(int* __restrict__ partials) {
    const int t = threadIdx.x;
    int v = (t < SCAN_NB) ? partials[t] : 0;
    __shared__ int sh[256];
    sh[t] = v;
    __syncthreads();
    for (int off = 1; off < 256; off <<= 1) {
        int u = (t >= off) ? sh[t - off] : 0;
        __syncthreads();
        sh[t] += u;
        __syncthreads();
    }
    if (t < SCAN_NB) partials[t] = sh[t] - v;
}

__global__ __launch_bounds__(256) void k_scan3(const int* __restrict__ excl,
                                               const int* __restrict__ partials,
                                               const int* __restrict__ deg,
                                               int* __restrict__ rowptr,
                                               float* __restrict__ inv_sqrt) {
    const int i = blockIdx.x * 256 + threadIdx.x;
    if (i < N_NODES) {
        rowptr[i] = excl[i] + partials[blockIdx.x];
        inv_sqrt[i] = rsqrtf((float)deg[i] + 1.0f);
    }
    if (i == 0) rowptr[N_NODES] = N_EDGES;
}

// ---------------------------------------------------------------------------
// all three W -> bf16 B-fragment packs in one launch (40960 elems, 160 blocks)
// ---------------------------------------------------------------------------
__global__ __launch_bounds__(256) void k_wconv_all(
    const float* __restrict__ W1, const float* __restrict__ W2,
    const float* __restrict__ W3,
    unsigned short* __restrict__ Wf1, unsigned short* __restrict__ Wf2,
    unsigned short* __restrict__ Wf3) {
    int gid = blockIdx.x * 256 + threadIdx.x;
    const float* W; unsigned short* Wf; int NCOL, idx;
    if (gid < 16384)      { W = W1; Wf = Wf1; NCOL = 128; idx = gid; }
    else if (gid < 32768) { W = W2; Wf = Wf2; NCOL = 128; idx = gid - 16384; }
    else                  { W = W3; Wf = Wf3; NCOL = 64;  idx = gid - 32768; }
    int j  = idx & 7;
    int l  = (idx >> 3) & 63;
    int s  = (idx >> 9) & 3;
    int tn = idx >> 11;
    int n = tn * 16 + (l & 15);
    int k = s * 32 + (l >> 4) * 8 + j;
    Wf[idx] = f2bf(W[k * NCOL + n]);
}

// ---------------------------------------------------------------------------
// MFMA GEMM body: H(bf16) = act(A) @ W, act = BN+ReLU if BN.
// ---------------------------------------------------------------------------
template <int NCOL, bool BN, bool ABF16>
static __device__ __forceinline__ void gemm_body(
    int row0, int t,
    const void* __restrict__ Ap, const unsigned short* __restrict__ Wf,
    const float* __restrict__ stats,
    const float* __restrict__ gamma, const float* __restrict__ beta,
    unsigned short* __restrict__ H,
    unsigned short* As, float* sc_s, float* sh_s) {
    if (BN) {
        if (t < 128) {
            float s  = stats[t];
            float sq = stats[128 + t];
            float mean = s * (1.0f / N_NODES);
            float var  = sq * (1.0f / N_NODES) - mean * mean;
            float sc = gamma[t] * rsqrtf(var + EPS);
            sc_s[t] = sc;
            sh_s[t] = beta[t] - mean * sc;
        }
        __syncthreads();
    }

    // ---- stage 64x128 A-tile into LDS as bf16 (BN+ReLU fused, fp32 math) ----
#pragma unroll
    for (int i = 0; i < 4; i++) {
        int q = i * 256 + t;
        int row = q >> 4;
        int c8  = (q & 15) * 8;
        int grow = row0 + row;
        float v[8];
        if (grow < N_NODES) {
            if (ABF16) {
                uint4 p = *(const uint4*)((const unsigned short*)Ap + (size_t)grow * 128 + c8);
                v[0] = blo(p.x); v[1] = bhi(p.x); v[2] = blo(p.y); v[3] = bhi(p.y);
                v[4] = blo(p.z); v[5] = bhi(p.z); v[6] = blo(p.w); v[7] = bhi(p.w);
            } else {
                const float* Af = (const float*)Ap + (size_t)grow * 128 + c8;
                float4 f0 = *(const float4*)Af;
                float4 f1 = *(const float4*)(Af + 4);
                v[0] = f0.x; v[1] = f0.y; v[2] = f0.z; v[3] = f0.w;
                v[4] = f1.x; v[5] = f1.y; v[6] = f1.z; v[7] = f1.w;
            }
        } else {
#pragma unroll
            for (int j = 0; j < 8; j++) v[j] = 0.f;
        }
        if (BN) {
#pragma unroll
            for (int j = 0; j < 8; j++)
                v[j] = fmaxf(fmaf(v[j], sc_s[c8 + j], sh_s[c8 + j]), 0.f);
        }
        uint4 pk;
        pk.x = (unsigned)f2bf(v[0]) | ((unsigned)f2bf(v[1]) << 16);
        pk.y = (unsigned)f2bf(v[2]) | ((unsigned)f2bf(v[3]) << 16);
        pk.z = (unsigned)f2bf(v[4]) | ((unsigned)f2bf(v[5]) << 16);
        pk.w = (unsigned)f2bf(v[6]) | ((unsigned)f2bf(v[7]) << 16);
        *(uint4*)&As[row * 136 + c8] = pk;
    }
    __syncthreads();

    // ---- fragments & MFMA ----
    const int wv = t >> 6;
    const int l  = t & 63;
    const int m  = l & 15;
    const int kq = l >> 4;

    bf16x8 afrag[4];
    const unsigned short* arow = &As[(wv * 16 + m) * 136 + kq * 8];
#pragma unroll
    for (int s = 0; s < 4; s++)
        afrag[s] = *(const bf16x8*)(arow + s * 32);

    constexpr int NT = NCOL / 16;
#pragma unroll
    for (int tn = 0; tn < NT; tn++) {
        f32x4 acc = {0.f, 0.f, 0.f, 0.f};
#pragma unroll
        for (int s = 0; s < 4; s++) {
            bf16x8 b = *(const bf16x8*)&Wf[(size_t)((tn * 4 + s) * 64 + l) * 8];
            acc = __builtin_amdgcn_mfma_f32_16x16x32_bf16(afrag[s], b, acc, 0, 0, 0);
        }
        int col = tn * 16 + m;
#pragma unroll
        for (int r = 0; r < 4; r++) {
            int row = row0 + wv * 16 + kq * 4 + r;
            if (row < N_NODES) H[(size_t)row * NCOL + col] = f2bf(acc[r]);
        }
    }
}

// standalone GEMM kernels for layers 2/3
template <int NCOL>
__global__ __launch_bounds__(256) void k_gemm_bn(
    const unsigned short* __restrict__ A, const unsigned short* __restrict__ Wf,
    const float* __restrict__ stats,
    const float* __restrict__ gamma, const float* __restrict__ beta,
    unsigned short* __restrict__ H) {
    __shared__ unsigned short As[64 * 136];
    __shared__ float sc_s[128], sh_s[128];
    gemm_body<NCOL, true, true>(blockIdx.x * 64, threadIdx.x, A, Wf, stats,
                                gamma, beta, H, As, sc_s, sh_s);
}

// ---------------------------------------------------------------------------
// fused: blocks [0,GEMM_NB) = layer-1 GEMM; blocks [GEMM_NB,...) = CSR fill
// (independent DAG branches; fill is latency-bound, GEMM is MFMA-bound)
// ---------------------------------------------------------------------------
__global__ __launch_bounds__(256) void k_gemm1_fill(
    const float* __restrict__ x, const unsigned short* __restrict__ Wf1,
    unsigned short* __restrict__ h1,
    const int* __restrict__ ei, const int* __restrict__ rank,
    const int* __restrict__ rowptr, int* __restrict__ esrc) {
    __shared__ unsigned short As[64 * 136];
    __shared__ float sc_s[128], sh_s[128];
    if (blockIdx.x < GEMM_NB) {
        gemm_body<128, false, false>(blockIdx.x * 64, threadIdx.x, x, Wf1,
                                     nullptr, nullptr, nullptr, h1, As, sc_s, sh_s);
    } else {
        int e0 = ((blockIdx.x - GEMM_NB) * 256 + threadIdx.x) * 4;
        if (e0 < N_EDGES) {
            int4 s4 = *(const int4*)&ei[e0];
            int4 d4 = *(const int4*)&ei[N_EDGES + e0];
            int4 r4 = *(const int4*)&rank[e0];
            // 4 independent L2 gathers + 4 fire-and-forget stores (no atomics)
            int p0 = rowptr[d4.x] + r4.x;
            int p1 = rowptr[d4.y] + r4.y;
            int p2 = rowptr[d4.z] + r4.z;
            int p3 = rowptr[d4.w] + r4.w;
            esrc[p0] = s4.x;
            esrc[p1] = s4.y;
            esrc[p2] = s4.z;
            esrc[p3] = s4.w;
        }
    }
}

// ---------------------------------------------------------------------------
// CSR gather-aggregate from bf16 H, fp32 accumulate, 4-wide unroll.
// coef computed on the fly: inv_sqrt[s] * inv_sqrt[node]
// ---------------------------------------------------------------------------
template <int F, bool OUTBF>
__global__ __launch_bounds__(256) void k_agg(const int* __restrict__ rowptr,
                                             const int* __restrict__ esrc,
                                             const float* __restrict__ inv_sqrt,
                                             const unsigned short* __restrict__ H,
                                             const float* __restrict__ bias,
                                             void* __restrict__ OUT) {
    constexpr int LPN = F / 4;              // lanes per node (32 or 16)
    constexpr int NPB = 256 / LPN;
    const int t = threadIdx.x;
    const int node = blockIdx.x * NPB + t / LPN;
    const int lane = t % LPN;
    if (node >= N_NODES) return;

    const uint2* __restrict__ Hv = (const uint2*)H;   // 4 bf16 per uint2
    const int beg = rowptr[node];
    const int end = rowptr[node + 1];
    const float rsn = inv_sqrt[node];

    float4 acc = make_float4(0.f, 0.f, 0.f, 0.f);
    int j = beg;
    for (; j + 3 < end; j += 4) {
        int s0 = esrc[j], s1 = esrc[j + 1], s2 = esrc[j + 2], s3 = esrc[j + 3];
        uint2 p0 = Hv[(size_t)s0 * LPN + lane];
        uint2 p1 = Hv[(size_t)s1 * LPN + lane];
        uint2 p2 = Hv[(size_t)s2 * LPN + lane];
        uint2 p3 = Hv[(size_t)s3 * LPN + lane];
        float c0 = inv_sqrt[s0] * rsn, c1 = inv_sqrt[s1] * rsn;
        float c2 = inv_sqrt[s2] * rsn, c3 = inv_sqrt[s3] * rsn;
        acc.x = fmaf(blo(p0.x), c0, acc.x); acc.y = fmaf(bhi(p0.x), c0, acc.y);
        acc.z = fmaf(blo(p0.y), c0, acc.z); acc.w = fmaf(bhi(p0.y), c0, acc.w);
        acc.x = fmaf(blo(p1.x), c1, acc.x); acc.y = fmaf(bhi(p1.x), c1, acc.y);
        acc.z = fmaf(blo(p1.y), c1, acc.z); acc.w = fmaf(bhi(p1.y), c1, acc.w);
        acc.x = fmaf(blo(p2.x), c2, acc.x); acc.y = fmaf(bhi(p2.x), c2, acc.y);
        acc.z = fmaf(blo(p2.y), c2, acc.z); acc.w = fmaf(bhi(p2.y), c2, acc.w);
        acc.x = fmaf(blo(p3.x), c3, acc.x); acc.y = fmaf(bhi(p3.x), c3, acc.y);
        acc.z = fmaf(blo(p3.y), c3, acc.z); acc.w = fmaf(bhi(p3.y), c3, acc.w);
    }
    for (; j < end; j++) {
        int s0 = esrc[j];
        float c0 = inv_sqrt[s0] * rsn;
        uint2 p0 = Hv[(size_t)s0 * LPN + lane];
        acc.x = fmaf(blo(p0.x), c0, acc.x); acc.y = fmaf(bhi(p0.x), c0, acc.y);
        acc.z = fmaf(blo(p0.y), c0, acc.z); acc.w = fmaf(bhi(p0.y), c0, acc.w);
    }

    // self-loop + bias (self coef = rsn^2)
    uint2 ps = Hv[(size_t)node * LPN + lane];
    float idv = rsn * rsn;
    float4 b4 = ((const float4*)bias)[lane];
    acc.x = fmaf(blo(ps.x), idv, acc.x) + b4.x;
    acc.y = fmaf(bhi(ps.x), idv, acc.y) + b4.y;
    acc.z = fmaf(blo(ps.y), idv, acc.z) + b4.z;
    acc.w = fmaf(bhi(ps.y), idv, acc.w) + b4.w;

    if (OUTBF) {
        uint2 pk;
        pk.x = (unsigned)f2bf(acc.x) | ((unsigned)f2bf(acc.y) << 16);
        pk.y = (unsigned)f2bf(acc.z) | ((unsigned)f2bf(acc.w) << 16);
        ((uint2*)OUT)[(size_t)node * LPN + lane] = pk;
    } else {
        ((float4*)OUT)[(size_t)node * LPN + lane] = acc;
    }
}

// ---------------------------------------------------------------------------
// column stats over bf16 A[N,128]
// ---------------------------------------------------------------------------
__global__ __launch_bounds__(256) void k_stats(const unsigned short* __restrict__ A,
                                               float* __restrict__ stats) {
    const int t  = threadIdx.x;
    const int c4 = t & 31;
    const int rr = t >> 5;
    float4 sum = make_float4(0.f, 0.f, 0.f, 0.f);
    float4 sq  = make_float4(0.f, 0.f, 0.f, 0.f);
    for (int row = blockIdx.x * 8 + rr; row < N_NODES; row += gridDim.x * 8) {
        uint2 p = *(const uint2*)&A[(size_t)row * 128 + c4 * 4];
        float vx = blo(p.x), vy = bhi(p.x), vz = blo(p.y), vw = bhi(p.y);
        sum.x += vx; sum.y += vy; sum.z += vz; sum.w += vw;
        sq.x += vx * vx; sq.y += vy * vy; sq.z += vz * vz; sq.w += vw * vw;
    }
    __shared__ float4 red[2][8][32];
    red[0][rr][c4] = sum;
    red[1][rr][c4] = sq;
    __syncthreads();
    if (t < 32) {
        float4 s = make_float4(0.f, 0.f, 0.f, 0.f);
        float4 q = make_float4(0.f, 0.f, 0.f, 0.f);
#pragma unroll
        for (int i = 0; i < 8; i++) {
            float4 a = red[0][i][t];
            float4 b = red[1][i][t];
            s.x += a.x; s.y += a.y; s.z += a.z; s.w += a.w;
            q.x += b.x; q.y += b.y; q.z += b.z; q.w += b.w;
        }
        int c = t * 4;
        atomicAdd(&stats[c + 0], s.x); atomicAdd(&stats[c + 1], s.y);
        atomicAdd(&stats[c + 2], s.z); atomicAdd(&stats[c + 3], s.w);
        atomicAdd(&stats[128 + c + 0], q.x); atomicAdd(&stats[128 + c + 1], q.y);
        atomicAdd(&stats[128 + c + 2], q.z); atomicAdd(&stats[128 + c + 3], q.w);
    }
}

// ---------------------------------------------------------------------------
extern "C" void kernel_launch(void* const* d_in, const int* in_sizes, int n_in,
                              void* d_out, int out_size, void* d_ws, size_t ws_size,
                              hipStream_t stream) {
    const float* x   = (const float*)d_in[0];
    const int*   ei  = (const int*)d_in[1];
    const float* W1  = (const float*)d_in[2];
    const float* b1  = (const float*)d_in[3];
    const float* g1  = (const float*)d_in[4];
    const float* bt1 = (const float*)d_in[5];
    const float* W2  = (const float*)d_in[6];
    const float* b2  = (const float*)d_in[7];
    const float* g2  = (const float*)d_in[8];
    const float* bt2 = (const float*)d_in[9];
    const float* W3  = (const float*)d_in[10];
    const float* b3  = (const float*)d_in[11];
    float* out = (float*)d_out;                 // [N, 64] fp32

    char* ws = (char*)d_ws;
    size_t off = 0;
    auto alloc = [&](size_t bytes) { char* p = ws + off; off += (bytes + 255) & ~(size_t)255; return p; };
    int*   deg      = (int*)  alloc((size_t)N_NODES * 4);
    float* inv_sqrt = (float*)alloc((size_t)N_NODES * 4);
    int*   excl     = (int*)  alloc((size_t)N_NODES * 4);
    int*   partials = (int*)  alloc(256 * 4);
    int*   rowptr   = (int*)  alloc((size_t)(N_NODES + 1) * 4);
    int*   rank     = (int*)  alloc((size_t)N_EDGES * 4);
    int*   esrc     = (int*)  alloc((size_t)N_EDGES * 4);
    float* stats1   = (float*)alloc(256 * 4);
    float* stats2   = (float*)alloc(256 * 4);
    unsigned short* Wf1 = (unsigned short*)alloc((size_t)128 * 128 * 2);
    unsigned short* Wf2 = (unsigned short*)alloc((size_t)128 * 128 * 2);
    unsigned short* Wf3 = (unsigned short*)alloc((size_t)64 * 128 * 2);
    unsigned short* h1  = (unsigned short*)alloc((size_t)N_NODES * 128 * 2);
    unsigned short* h2  = (unsigned short*)alloc((size_t)N_NODES * 128 * 2);
    unsigned short* h3  = (unsigned short*)alloc((size_t)N_NODES * 64 * 2);
    unsigned short* agg1 = (unsigned short*)alloc((size_t)N_NODES * 128 * 2);
    unsigned short* agg2 = (unsigned short*)alloc((size_t)N_NODES * 128 * 2);

    hipMemsetAsync(deg, 0, (size_t)N_NODES * 4, stream);
    hipMemsetAsync(stats1, 0, 256 * 4, stream);
    hipMemsetAsync(stats2, 0, 256 * 4, stream);

    k_prep<<<FILL_NB, 256, 0, stream>>>(ei, deg, rank);
    k_scan1<<<SCAN_NB, 256, 0, stream>>>(deg, excl, partials);
    k_scan2<<<1, 256, 0, stream>>>(partials);
    k_scan3<<<SCAN_NB, 256, 0, stream>>>(excl, partials, deg, rowptr, inv_sqrt);
    k_wconv_all<<<160, 256, 0, stream>>>(W1, W2, W3, Wf1, Wf2, Wf3);

    // layer-1 GEMM fused with CSR fill (independent DAG branches)
    k_gemm1_fill<<<GEMM_NB + FILL_NB, 256, 0, stream>>>(x, Wf1, h1, ei, rank, rowptr, esrc);

    // layer 1 aggregate
    k_agg<128, true><<<(N_NODES + 7) / 8, 256, 0, stream>>>(rowptr, esrc, inv_sqrt, h1, b1, agg1);
    k_stats<<<256, 256, 0, stream>>>(agg1, stats1);

    // layer 2
    k_gemm_bn<128><<<GEMM_NB, 256, 0, stream>>>(agg1, Wf2, stats1, g1, bt1, h2);
    k_agg<128, true><<<(N_NODES + 7) / 8, 256, 0, stream>>>(rowptr, esrc, inv_sqrt, h2, b2, agg2);
    k_stats<<<256, 256, 0, stream>>>(agg2, stats2);

    // layer 3 (aggregate straight into d_out, fp32)
    k_gemm_bn<64><<<GEMM_NB, 256, 0, stream>>>(agg2, Wf3, stats2, g2, bt2, h3);
    k_agg<64, false><<<(N_NODES + 15) / 16, 256, 0, stream>>>(rowptr, esrc, inv_sqrt, h3, b3, out);
}

// Round 8
// 320.625 us; speedup vs baseline: 1.1949x; 1.0559x over previous
//
#include <hip/hip_runtime.h>

#define N_NODES 50000
#define N_EDGES 800000
static constexpr float EPS = 1e-5f;
static constexpr int SCAN_NB = (N_NODES + 255) / 256;   // 196
static constexpr int GEMM_NB = (N_NODES + 63) / 64;     // 782
static constexpr int FILL_NB = (N_EDGES + 1023) / 1024; // 782 (4 edges/thread)

using bf16x8 = __attribute__((ext_vector_type(8))) short;  // 8 bf16 (4 VGPRs)
using f32x4  = __attribute__((ext_vector_type(4))) float;

// ---- bf16 helpers (raw-bit, RNE) ----
static __device__ __forceinline__ unsigned short f2bf(float f) {
    unsigned int u = __float_as_uint(f);
    return (unsigned short)((u + 0x7FFFu + ((u >> 16) & 1u)) >> 16);
}
static __device__ __forceinline__ float blo(unsigned int w) { return __uint_as_float(w << 16); }
static __device__ __forceinline__ float bhi(unsigned int w) { return __uint_as_float(w & 0xffff0000u); }

// ---------------------------------------------------------------------------
// fused: blocks [0,FILL_NB) = in-degree histogram + per-edge rank;
//        blocks [FILL_NB, FILL_NB+160) = W->bf16 fragment packing (independent)
// ---------------------------------------------------------------------------
__global__ __launch_bounds__(256) void k_prep_wconv(
    const int* __restrict__ ei, int* __restrict__ deg, int* __restrict__ rank,
    const float* __restrict__ W1, const float* __restrict__ W2,
    const float* __restrict__ W3,
    unsigned short* __restrict__ Wf1, unsigned short* __restrict__ Wf2,
    unsigned short* __restrict__ Wf3) {
    if (blockIdx.x < FILL_NB) {
        int e0 = (blockIdx.x * 256 + threadIdx.x) * 4;
        if (e0 >= N_EDGES) return;          // N_EDGES % 4 == 0
        int4 d4 = *(const int4*)&ei[N_EDGES + e0];
        int4 r;
        r.x = atomicAdd(&deg[d4.x], 1);
        r.y = atomicAdd(&deg[d4.y], 1);
        r.z = atomicAdd(&deg[d4.z], 1);
        r.w = atomicAdd(&deg[d4.w], 1);
        *(int4*)&rank[e0] = r;
    } else {
        int gid = (blockIdx.x - FILL_NB) * 256 + threadIdx.x;   // < 40960
        const float* W; unsigned short* Wf; int NCOL, idx;
        if (gid < 16384)      { W = W1; Wf = Wf1; NCOL = 128; idx = gid; }
        else if (gid < 32768) { W = W2; Wf = Wf2; NCOL = 128; idx = gid - 16384; }
        else                  { W = W3; Wf = Wf3; NCOL = 64;  idx = gid - 32768; }
        int j  = idx & 7;
        int l  = (idx >> 3) & 63;
        int s  = (idx >> 9) & 3;
        int tn = idx >> 11;
        int n = tn * 16 + (l & 15);
        int k = s * 32 + (l >> 4) * 8 + j;
        Wf[idx] = f2bf(W[k * NCOL + n]);
    }
}

// ---------------------------------------------------------------------------
// scan stage 1: block-local exclusive scan + block totals
// ---------------------------------------------------------------------------
__global__ __launch_bounds__(256) void k_scan1(const int* __restrict__ deg,
                                               int* __restrict__ excl,
                                               int* __restrict__ partials) {
    const int t = threadIdx.x;
    const int i = blockIdx.x * 256 + t;
    int v = (i < N_NODES) ? deg[i] : 0;
    __shared__ int sh[256];
    sh[t] = v;
    __syncthreads();
    for (int off = 1; off < 256; off <<= 1) {
        int u = (t >= off) ? sh[t - off] : 0;
        __syncthreads();
        sh[t] += u;
        __syncthreads();
    }
    if (i < N_NODES) excl[i] = sh[t] - v;
    if (t == 255) partials[blockIdx.x] = sh[t];
}

// stages 2+3 fused: every block redundantly scans the 196 partials (784 B),
// derives its own offset, applies -> rowptr + inv_sqrt
__global__ __launch_bounds__(256) void k_scan23(const int* __restrict__ excl,
                                                const int* __restrict__ partials,
                                                const int* __restrict__ deg,
                                                int* __restrict__ rowptr,
                                                float* __restrict__ inv_sqrt) {
    const int t = threadIdx.x;
    int v = (t < SCAN_NB) ? partials[t] : 0;
    __shared__ int sh[256];
    __shared__ int base_s;
    sh[t] = v;
    __syncthreads();
    for (int off = 1; off < 256; off <<= 1) {
        int u = (t >= off) ? sh[t - off] : 0;
        __syncthreads();
        sh[t] += u;
        __syncthreads();
    }
    if (t == blockIdx.x) base_s = sh[t] - v;   // exclusive prefix of this block
    __syncthreads();
    const int base = base_s;
    const int i = blockIdx.x * 256 + t;
    if (i < N_NODES) {
        rowptr[i] = excl[i] + base;
        inv_sqrt[i] = rsqrtf((float)deg[i] + 1.0f);
    }
    if (i == 0) rowptr[N_NODES] = N_EDGES;
}

// ---------------------------------------------------------------------------
// MFMA GEMM body: H(bf16) = act(A) @ W, act = BN+ReLU if BN.
// ---------------------------------------------------------------------------
template <int NCOL, bool BN, bool ABF16>
static __device__ __forceinline__ void gemm_body(
    int row0, int t,
    const void* __restrict__ Ap, const unsigned short* __restrict__ Wf,
    const float* __restrict__ stats,
    const float* __restrict__ gamma, const float* __restrict__ beta,
    unsigned short* __restrict__ H,
    unsigned short* As, float* sc_s, float* sh_s) {
    if (BN) {
        if (t < 128) {
            float s  = stats[t];
            float sq = stats[128 + t];
            float mean = s * (1.0f / N_NODES);
            float var  = sq * (1.0f / N_NODES) - mean * mean;
            float sc = gamma[t] * rsqrtf(var + EPS);
            sc_s[t] = sc;
            sh_s[t] = beta[t] - mean * sc;
        }
        __syncthreads();
    }

    // ---- stage 64x128 A-tile into LDS as bf16 (BN+ReLU fused, fp32 math) ----
#pragma unroll
    for (int i = 0; i < 4; i++) {
        int q = i * 256 + t;
        int row = q >> 4;
        int c8  = (q & 15) * 8;
        int grow = row0 + row;
        float v[8];
        if (grow < N_NODES) {
            if (ABF16) {
                uint4 p = *(const uint4*)((const unsigned short*)Ap + (size_t)grow * 128 + c8);
                v[0] = blo(p.x); v[1] = bhi(p.x); v[2] = blo(p.y); v[3] = bhi(p.y);
                v[4] = blo(p.z); v[5] = bhi(p.z); v[6] = blo(p.w); v[7] = bhi(p.w);
            } else {
                const float* Af = (const float*)Ap + (size_t)grow * 128 + c8;
                float4 f0 = *(const float4*)Af;
                float4 f1 = *(const float4*)(Af + 4);
                v[0] = f0.x; v[1] = f0.y; v[2] = f0.z; v[3] = f0.w;
                v[4] = f1.x; v[5] = f1.y; v[6] = f1.z; v[7] = f1.w;
            }
        } else {
#pragma unroll
            for (int j = 0; j < 8; j++) v[j] = 0.f;
        }
        if (BN) {
#pragma unroll
            for (int j = 0; j < 8; j++)
                v[j] = fmaxf(fmaf(v[j], sc_s[c8 + j], sh_s[c8 + j]), 0.f);
        }
        uint4 pk;
        pk.x = (unsigned)f2bf(v[0]) | ((unsigned)f2bf(v[1]) << 16);
        pk.y = (unsigned)f2bf(v[2]) | ((unsigned)f2bf(v[3]) << 16);
        pk.z = (unsigned)f2bf(v[4]) | ((unsigned)f2bf(v[5]) << 16);
        pk.w = (unsigned)f2bf(v[6]) | ((unsigned)f2bf(v[7]) << 16);
        *(uint4*)&As[row * 136 + c8] = pk;
    }
    __syncthreads();

    // ---- fragments & MFMA ----
    const int wv = t >> 6;
    const int l  = t & 63;
    const int m  = l & 15;
    const int kq = l >> 4;

    bf16x8 afrag[4];
    const unsigned short* arow = &As[(wv * 16 + m) * 136 + kq * 8];
#pragma unroll
    for (int s = 0; s < 4; s++)
        afrag[s] = *(const bf16x8*)(arow + s * 32);

    constexpr int NT = NCOL / 16;
#pragma unroll
    for (int tn = 0; tn < NT; tn++) {
        f32x4 acc = {0.f, 0.f, 0.f, 0.f};
#pragma unroll
        for (int s = 0; s < 4; s++) {
            bf16x8 b = *(const bf16x8*)&Wf[(size_t)((tn * 4 + s) * 64 + l) * 8];
            acc = __builtin_amdgcn_mfma_f32_16x16x32_bf16(afrag[s], b, acc, 0, 0, 0);
        }
        int col = tn * 16 + m;
#pragma unroll
        for (int r = 0; r < 4; r++) {
            int row = row0 + wv * 16 + kq * 4 + r;
            if (row < N_NODES) H[(size_t)row * NCOL + col] = f2bf(acc[r]);
        }
    }
}

// standalone GEMM kernels for layers 2/3
template <int NCOL>
__global__ __launch_bounds__(256) void k_gemm_bn(
    const unsigned short* __restrict__ A, const unsigned short* __restrict__ Wf,
    const float* __restrict__ stats,
    const float* __restrict__ gamma, const float* __restrict__ beta,
    unsigned short* __restrict__ H) {
    __shared__ unsigned short As[64 * 136];
    __shared__ float sc_s[128], sh_s[128];
    gemm_body<NCOL, true, true>(blockIdx.x * 64, threadIdx.x, A, Wf, stats,
                                gamma, beta, H, As, sc_s, sh_s);
}

// ---------------------------------------------------------------------------
// fused: blocks [0,GEMM_NB) = layer-1 GEMM; blocks [GEMM_NB,...) = CSR fill
// ---------------------------------------------------------------------------
__global__ __launch_bounds__(256) void k_gemm1_fill(
    const float* __restrict__ x, const unsigned short* __restrict__ Wf1,
    unsigned short* __restrict__ h1,
    const int* __restrict__ ei, const int* __restrict__ rank,
    const int* __restrict__ rowptr, int* __restrict__ esrc) {
    __shared__ unsigned short As[64 * 136];
    __shared__ float sc_s[128], sh_s[128];
    if (blockIdx.x < GEMM_NB) {
        gemm_body<128, false, false>(blockIdx.x * 64, threadIdx.x, x, Wf1,
                                     nullptr, nullptr, nullptr, h1, As, sc_s, sh_s);
    } else {
        int e0 = ((blockIdx.x - GEMM_NB) * 256 + threadIdx.x) * 4;
        if (e0 < N_EDGES) {
            int4 s4 = *(const int4*)&ei[e0];
            int4 d4 = *(const int4*)&ei[N_EDGES + e0];
            int4 r4 = *(const int4*)&rank[e0];
            int p0 = rowptr[d4.x] + r4.x;
            int p1 = rowptr[d4.y] + r4.y;
            int p2 = rowptr[d4.z] + r4.z;
            int p3 = rowptr[d4.w] + r4.w;
            esrc[p0] = s4.x;
            esrc[p1] = s4.y;
            esrc[p2] = s4.z;
            esrc[p3] = s4.w;
        }
    }
}

// ---------------------------------------------------------------------------
// CSR gather-aggregate from bf16 H, fp32 accumulate, 4-wide edge unroll,
// 16 B/lane (uint4 = 8 bf16). coef = inv_sqrt[s] * inv_sqrt[node] on the fly.
// ---------------------------------------------------------------------------
template <int F, bool OUTBF>
__global__ __launch_bounds__(256) void k_agg(const int* __restrict__ rowptr,
                                             const int* __restrict__ esrc,
                                             const float* __restrict__ inv_sqrt,
                                             const unsigned short* __restrict__ H,
                                             const float* __restrict__ bias,
                                             void* __restrict__ OUT) {
    constexpr int LPN = F / 8;              // lanes per node (16 or 8), uint4 each
    constexpr int NPB = 256 / LPN;          // nodes per block (16 or 32)
    const int t = threadIdx.x;
    const int node = blockIdx.x * NPB + t / LPN;
    const int lane = t % LPN;
    if (node >= N_NODES) return;

    const uint4* __restrict__ Hv = (const uint4*)H;   // 8 bf16 per uint4
    const int beg = rowptr[node];
    const int end = rowptr[node + 1];
    const float rsn = inv_sqrt[node];

    float acc[8];
#pragma unroll
    for (int i = 0; i < 8; i++) acc[i] = 0.f;

#define ACC8(P, C)                                                     \
    acc[0] = fmaf(blo((P).x), (C), acc[0]);                            \
    acc[1] = fmaf(bhi((P).x), (C), acc[1]);                            \
    acc[2] = fmaf(blo((P).y), (C), acc[2]);                            \
    acc[3] = fmaf(bhi((P).y), (C), acc[3]);                            \
    acc[4] = fmaf(blo((P).z), (C), acc[4]);                            \
    acc[5] = fmaf(bhi((P).z), (C), acc[5]);                            \
    acc[6] = fmaf(blo((P).w), (C), acc[6]);                            \
    acc[7] = fmaf(bhi((P).w), (C), acc[7]);

    int j = beg;
    for (; j + 3 < end; j += 4) {
        int s0 = esrc[j], s1 = esrc[j + 1], s2 = esrc[j + 2], s3 = esrc[j + 3];
        uint4 p0 = Hv[(size_t)s0 * LPN + lane];
        uint4 p1 = Hv[(size_t)s1 * LPN + lane];
        uint4 p2 = Hv[(size_t)s2 * LPN + lane];
        uint4 p3 = Hv[(size_t)s3 * LPN + lane];
        float c0 = inv_sqrt[s0] * rsn, c1 = inv_sqrt[s1] * rsn;
        float c2 = inv_sqrt[s2] * rsn, c3 = inv_sqrt[s3] * rsn;
        ACC8(p0, c0) ACC8(p1, c1) ACC8(p2, c2) ACC8(p3, c3)
    }
    for (; j < end; j++) {
        int s0 = esrc[j];
        float c0 = inv_sqrt[s0] * rsn;
        uint4 p0 = Hv[(size_t)s0 * LPN + lane];
        ACC8(p0, c0)
    }
#undef ACC8

    // self-loop + bias (self coef = rsn^2)
    uint4 ps = Hv[(size_t)node * LPN + lane];
    float idv = rsn * rsn;
    float4 b0 = ((const float4*)bias)[lane * 2];
    float4 b1 = ((const float4*)bias)[lane * 2 + 1];
    acc[0] = fmaf(blo(ps.x), idv, acc[0]) + b0.x;
    acc[1] = fmaf(bhi(ps.x), idv, acc[1]) + b0.y;
    acc[2] = fmaf(blo(ps.y), idv, acc[2]) + b0.z;
    acc[3] = fmaf(bhi(ps.y), idv, acc[3]) + b0.w;
    acc[4] = fmaf(blo(ps.z), idv, acc[4]) + b1.x;
    acc[5] = fmaf(bhi(ps.z), idv, acc[5]) + b1.y;
    acc[6] = fmaf(blo(ps.w), idv, acc[6]) + b1.z;
    acc[7] = fmaf(bhi(ps.w), idv, acc[7]) + b1.w;

    if (OUTBF) {
        uint4 pk;
        pk.x = (unsigned)f2bf(acc[0]) | ((unsigned)f2bf(acc[1]) << 16);
        pk.y = (unsigned)f2bf(acc[2]) | ((unsigned)f2bf(acc[3]) << 16);
        pk.z = (unsigned)f2bf(acc[4]) | ((unsigned)f2bf(acc[5]) << 16);
        pk.w = (unsigned)f2bf(acc[6]) | ((unsigned)f2bf(acc[7]) << 16);
        ((uint4*)OUT)[(size_t)node * LPN + lane] = pk;
    } else {
        float4* o = (float4*)OUT + ((size_t)node * LPN + lane) * 2;
        o[0] = make_float4(acc[0], acc[1], acc[2], acc[3]);
        o[1] = make_float4(acc[4], acc[5], acc[6], acc[7]);
    }
}

// ---------------------------------------------------------------------------
// column stats over bf16 A[N,128]
// ---------------------------------------------------------------------------
__global__ __launch_bounds__(256) void k_stats(const unsigned short* __restrict__ A,
                                               float* __restrict__ stats) {
    const int t  = threadIdx.x;
    const int c4 = t & 31;
    const int rr = t >> 5;
    float4 sum = make_float4(0.f, 0.f, 0.f, 0.f);
    float4 sq  = make_float4(0.f, 0.f, 0.f, 0.f);
    for (int row = blockIdx.x * 8 + rr; row < N_NODES; row += gridDim.x * 8) {
        uint2 p = *(const uint2*)&A[(size_t)row * 128 + c4 * 4];
        float vx = blo(p.x), vy = bhi(p.x), vz = blo(p.y), vw = bhi(p.y);
        sum.x += vx; sum.y += vy; sum.z += vz; sum.w += vw;
        sq.x += vx * vx; sq.y += vy * vy; sq.z += vz * vz; sq.w += vw * vw;
    }
    __shared__ float4 red[2][8][32];
    red[0][rr][c4] = sum;
    red[1][rr][c4] = sq;
    __syncthreads();
    if (t < 32) {
        float4 s = make_float4(0.f, 0.f, 0.f, 0.f);
        float4 q = make_float4(0.f, 0.f, 0.f, 0.f);
#pragma unroll
        for (int i = 0; i < 8; i++) {
            float4 a = red[0][i][t];
            float4 b = red[1][i][t];
            s.x += a.x; s.y += a.y; s.z += a.z; s.w += a.w;
            q.x += b.x; q.y += b.y; q.z += b.z; q.w += b.w;
        }
        int c = t * 4;
        atomicAdd(&stats[c + 0], s.x); atomicAdd(&stats[c + 1], s.y);
        atomicAdd(&stats[c + 2], s.z); atomicAdd(&stats[c + 3], s.w);
        atomicAdd(&stats[128 + c + 0], q.x); atomicAdd(&stats[128 + c + 1], q.y);
        atomicAdd(&stats[128 + c + 2], q.z); atomicAdd(&stats[128 + c + 3], q.w);
    }
}

// ---------------------------------------------------------------------------
extern "C" void kernel_launch(void* const* d_in, const int* in_sizes, int n_in,
                              void* d_out, int out_size, void* d_ws, size_t ws_size,
                              hipStream_t stream) {
    const float* x   = (const float*)d_in[0];
    const int*   ei  = (const int*)d_in[1];
    const float* W1  = (const float*)d_in[2];
    const float* b1  = (const float*)d_in[3];
    const float* g1  = (const float*)d_in[4];
    const float* bt1 = (const float*)d_in[5];
    const float* W2  = (const float*)d_in[6];
    const float* b2  = (const float*)d_in[7];
    const float* g2  = (const float*)d_in[8];
    const float* bt2 = (const float*)d_in[9];
    const float* W3  = (const float*)d_in[10];
    const float* b3  = (const float*)d_in[11];
    float* out = (float*)d_out;                 // [N, 64] fp32

    char* ws = (char*)d_ws;
    size_t off = 0;
    auto alloc = [&](size_t bytes) { char* p = ws + off; off += (bytes + 255) & ~(size_t)255; return p; };
    // contiguous zero-init region: deg | stats1 | stats2 (single memset)
    int*   deg      = (int*)  alloc((size_t)N_NODES * 4);   // 200192 padded
    float* stats1   = (float*)alloc(256 * 4);
    float* stats2   = (float*)alloc(256 * 4);
    const size_t zbytes = (size_t)((char*)(stats2 + 256) - (char*)deg);
    float* inv_sqrt = (float*)alloc((size_t)N_NODES * 4);
    int*   excl     = (int*)  alloc((size_t)N_NODES * 4);
    int*   partials = (int*)  alloc(256 * 4);
    int*   rowptr   = (int*)  alloc((size_t)(N_NODES + 1) * 4);
    int*   rank     = (int*)  alloc((size_t)N_EDGES * 4);
    int*   esrc     = (int*)  alloc((size_t)N_EDGES * 4);
    unsigned short* Wf1 = (unsigned short*)alloc((size_t)128 * 128 * 2);
    unsigned short* Wf2 = (unsigned short*)alloc((size_t)128 * 128 * 2);
    unsigned short* Wf3 = (unsigned short*)alloc((size_t)64 * 128 * 2);
    unsigned short* h1  = (unsigned short*)alloc((size_t)N_NODES * 128 * 2);
    unsigned short* h2  = (unsigned short*)alloc((size_t)N_NODES * 128 * 2);
    unsigned short* h3  = (unsigned short*)alloc((size_t)N_NODES * 64 * 2);
    unsigned short* agg1 = (unsigned short*)alloc((size_t)N_NODES * 128 * 2);
    unsigned short* agg2 = (unsigned short*)alloc((size_t)N_NODES * 128 * 2);

    hipMemsetAsync(deg, 0, zbytes, stream);

    k_prep_wconv<<<FILL_NB + 160, 256, 0, stream>>>(ei, deg, rank, W1, W2, W3,
                                                    Wf1, Wf2, Wf3);
    k_scan1<<<SCAN_NB, 256, 0, stream>>>(deg, excl, partials);
    k_scan23<<<SCAN_NB, 256, 0, stream>>>(excl, partials, deg, rowptr, inv_sqrt);

    // layer-1 GEMM fused with CSR fill (independent DAG branches)
    k_gemm1_fill<<<GEMM_NB + FILL_NB, 256, 0, stream>>>(x, Wf1, h1, ei, rank, rowptr, esrc);

    // layer 1 aggregate
    k_agg<128, true><<<N_NODES / 16, 256, 0, stream>>>(rowptr, esrc, inv_sqrt, h1, b1, agg1);
    k_stats<<<256, 256, 0, stream>>>(agg1, stats1);

    // layer 2
    k_gemm_bn<128><<<GEMM_NB, 256, 0, stream>>>(agg1, Wf2, stats1, g1, bt1, h2);
    k_agg<128, true><<<N_NODES / 16, 256, 0, stream>>>(rowptr, esrc, inv_sqrt, h2, b2, agg2);
    k_stats<<<256, 256, 0, stream>>>(agg2, stats2);

    // layer 3 (aggregate straight into d_out, fp32)
    k_gemm_bn<64><<<GEMM_NB, 256, 0, stream>>>(agg2, Wf3, stats2, g2, bt2, h3);
    k_agg<64, false><<<(N_NODES + 31) / 32, 256, 0, stream>>>(rowptr, esrc, inv_sqrt, h3, b3, out);
}

// Round 9
// 315.706 us; speedup vs baseline: 1.2135x; 1.0156x over previous
//
#include <hip/hip_runtime.h>

#define N_NODES 50000
#define N_EDGES 800000
static constexpr float EPS = 1e-5f;
static constexpr int NP = 50048;                        // padded node stride (ints)
static constexpr int NCHUNK = 7;                        // 800000 >> 17 = 6 (7 chunks)
static constexpr int SCAN_NB = (N_NODES + 255) / 256;   // 196
static constexpr int GEMM_NB = (N_NODES + 63) / 64;     // 782
static constexpr int FILL_NB = (N_EDGES + 1023) / 1024; // 782 (4 edges/thread)

using bf16x8 = __attribute__((ext_vector_type(8))) short;  // 8 bf16 (4 VGPRs)
using f32x4  = __attribute__((ext_vector_type(4))) float;

// ---- bf16 helpers (raw-bit, RNE) ----
static __device__ __forceinline__ unsigned short f2bf(float f) {
    unsigned int u = __float_as_uint(f);
    return (unsigned short)((u + 0x7FFFu + ((u >> 16) & 1u)) >> 16);
}
static __device__ __forceinline__ float blo(unsigned int w) { return __uint_as_float(w << 16); }
static __device__ __forceinline__ float bhi(unsigned int w) { return __uint_as_float(w & 0xffff0000u); }

// ---------------------------------------------------------------------------
// W -> bf16 fragment packing (all three layers, one tiny launch)
// ---------------------------------------------------------------------------
__global__ __launch_bounds__(256) void k_wconv_all(
    const float* __restrict__ W1, const float* __restrict__ W2,
    const float* __restrict__ W3,
    unsigned short* __restrict__ Wf1, unsigned short* __restrict__ Wf2,
    unsigned short* __restrict__ Wf3) {
    int gid = blockIdx.x * 256 + threadIdx.x;   // < 40960
    const float* W; unsigned short* Wf; int NCOL, idx;
    if (gid < 16384)      { W = W1; Wf = Wf1; NCOL = 128; idx = gid; }
    else if (gid < 32768) { W = W2; Wf = Wf2; NCOL = 128; idx = gid - 16384; }
    else                  { W = W3; Wf = Wf3; NCOL = 64;  idx = gid - 32768; }
    int j  = idx & 7;
    int l  = (idx >> 3) & 63;
    int s  = (idx >> 9) & 3;
    int tn = idx >> 11;
    int n = tn * 16 + (l & 15);
    int k = s * 32 + (l >> 4) * 8 + j;
    Wf[idx] = f2bf(W[k * NCOL + n]);
}

// ---------------------------------------------------------------------------
// MFMA GEMM body: H(bf16) = act(A) @ W, act = BN+ReLU if BN.
// ---------------------------------------------------------------------------
template <int NCOL, bool BN, bool ABF16>
static __device__ __forceinline__ void gemm_body(
    int row0, int t,
    const void* __restrict__ Ap, const unsigned short* __restrict__ Wf,
    const float* __restrict__ stats,
    const float* __restrict__ gamma, const float* __restrict__ beta,
    unsigned short* __restrict__ H,
    unsigned short* As, float* sc_s, float* sh_s) {
    if (BN) {
        if (t < 128) {
            float s  = stats[t];
            float sq = stats[128 + t];
            float mean = s * (1.0f / N_NODES);
            float var  = sq * (1.0f / N_NODES) - mean * mean;
            float sc = gamma[t] * rsqrtf(var + EPS);
            sc_s[t] = sc;
            sh_s[t] = beta[t] - mean * sc;
        }
        __syncthreads();
    }

    // ---- stage 64x128 A-tile into LDS as bf16 (BN+ReLU fused, fp32 math) ----
#pragma unroll
    for (int i = 0; i < 4; i++) {
        int q = i * 256 + t;
        int row = q >> 4;
        int c8  = (q & 15) * 8;
        int grow = row0 + row;
        float v[8];
        if (grow < N_NODES) {
            if (ABF16) {
                uint4 p = *(const uint4*)((const unsigned short*)Ap + (size_t)grow * 128 + c8);
                v[0] = blo(p.x); v[1] = bhi(p.x); v[2] = blo(p.y); v[3] = bhi(p.y);
                v[4] = blo(p.z); v[5] = bhi(p.z); v[6] = blo(p.w); v[7] = bhi(p.w);
            } else {
                const float* Af = (const float*)Ap + (size_t)grow * 128 + c8;
                float4 f0 = *(const float4*)Af;
                float4 f1 = *(const float4*)(Af + 4);
                v[0] = f0.x; v[1] = f0.y; v[2] = f0.z; v[3] = f0.w;
                v[4] = f1.x; v[5] = f1.y; v[6] = f1.z; v[7] = f1.w;
            }
        } else {
#pragma unroll
            for (int j = 0; j < 8; j++) v[j] = 0.f;
        }
        if (BN) {
#pragma unroll
            for (int j = 0; j < 8; j++)
                v[j] = fmaxf(fmaf(v[j], sc_s[c8 + j], sh_s[c8 + j]), 0.f);
        }
        uint4 pk;
        pk.x = (unsigned)f2bf(v[0]) | ((unsigned)f2bf(v[1]) << 16);
        pk.y = (unsigned)f2bf(v[2]) | ((unsigned)f2bf(v[3]) << 16);
        pk.z = (unsigned)f2bf(v[4]) | ((unsigned)f2bf(v[5]) << 16);
        pk.w = (unsigned)f2bf(v[6]) | ((unsigned)f2bf(v[7]) << 16);
        *(uint4*)&As[row * 136 + c8] = pk;
    }
    __syncthreads();

    // ---- fragments & MFMA ----
    const int wv = t >> 6;
    const int l  = t & 63;
    const int m  = l & 15;
    const int kq = l >> 4;

    bf16x8 afrag[4];
    const unsigned short* arow = &As[(wv * 16 + m) * 136 + kq * 8];
#pragma unroll
    for (int s = 0; s < 4; s++)
        afrag[s] = *(const bf16x8*)(arow + s * 32);

    constexpr int NT = NCOL / 16;
#pragma unroll
    for (int tn = 0; tn < NT; tn++) {
        f32x4 acc = {0.f, 0.f, 0.f, 0.f};
#pragma unroll
        for (int s = 0; s < 4; s++) {
            bf16x8 b = *(const bf16x8*)&Wf[(size_t)((tn * 4 + s) * 64 + l) * 8];
            acc = __builtin_amdgcn_mfma_f32_16x16x32_bf16(afrag[s], b, acc, 0, 0, 0);
        }
        int col = tn * 16 + m;
#pragma unroll
        for (int r = 0; r < 4; r++) {
            int row = row0 + wv * 16 + kq * 4 + r;
            if (row < N_NODES) H[(size_t)row * NCOL + col] = f2bf(acc[r]);
        }
    }
}

// standalone GEMM kernels for layers 2/3
template <int NCOL>
__global__ __launch_bounds__(256) void k_gemm_bn(
    const unsigned short* __restrict__ A, const unsigned short* __restrict__ Wf,
    const float* __restrict__ stats,
    const float* __restrict__ gamma, const float* __restrict__ beta,
    unsigned short* __restrict__ H) {
    __shared__ unsigned short As[64 * 136];
    __shared__ float sc_s[128], sh_s[128];
    gemm_body<NCOL, true, true>(blockIdx.x * 64, threadIdx.x, A, Wf, stats,
                                gamma, beta, H, As, sc_s, sh_s);
}

// ---------------------------------------------------------------------------
// fused: blocks [0,FILL_NB) = chunked histogram + per-edge rank (TCC-atomic
// bound); blocks [FILL_NB, +GEMM_NB) = layer-1 GEMM (MFMA bound). Independent
// DAG branches on different pipes -> dispatch ~ max, not sum.
// deg8 layout: [NCHUNK][NP], chunk = edge >> 17 (collisions/addr ~2.3 vs 16)
// ---------------------------------------------------------------------------
__global__ __launch_bounds__(256) void k_prep_gemm1(
    const int* __restrict__ ei, int* __restrict__ deg8, int* __restrict__ rank,
    const float* __restrict__ x, const unsigned short* __restrict__ Wf1,
    unsigned short* __restrict__ h1) {
    __shared__ unsigned short As[64 * 136];
    __shared__ float sc_s[128], sh_s[128];
    if (blockIdx.x < FILL_NB) {
        int e0 = (blockIdx.x * 256 + threadIdx.x) * 4;
        if (e0 >= N_EDGES) return;          // N_EDGES % 4 == 0
        int* dchunk = deg8 + (e0 >> 17) * NP;   // chunk-private sub-histogram
        int4 d4 = *(const int4*)&ei[N_EDGES + e0];
        int4 r;
        r.x = atomicAdd(&dchunk[d4.x], 1);
        r.y = atomicAdd(&dchunk[d4.y], 1);
        r.z = atomicAdd(&dchunk[d4.z], 1);
        r.w = atomicAdd(&dchunk[d4.w], 1);
        *(int4*)&rank[e0] = r;
    } else {
        gemm_body<128, false, false>((blockIdx.x - FILL_NB) * 64, threadIdx.x,
                                     x, Wf1, nullptr, nullptr, nullptr, h1,
                                     As, sc_s, sh_s);
    }
}

// ---------------------------------------------------------------------------
// scan stage 1: per-node total over chunks, in-place exclusive chunk bases,
// inv_sqrt, block-local exclusive scan of totals + block partials.
// ---------------------------------------------------------------------------
__global__ __launch_bounds__(256) void k_scan1(int* __restrict__ deg8,
                                               float* __restrict__ inv_sqrt,
                                               int* __restrict__ excl,
                                               int* __restrict__ partials) {
    const int t = threadIdx.x;
    const int i = blockIdx.x * 256 + t;
    int tot = 0;
    if (i < N_NODES) {
        int cb[NCHUNK];
        int run = 0;
#pragma unroll
        for (int c = 0; c < NCHUNK; c++) {
            int v = deg8[c * NP + i];
            cb[c] = run;
            run += v;
        }
        tot = run;
#pragma unroll
        for (int c = 0; c < NCHUNK; c++) deg8[c * NP + i] = cb[c];
        inv_sqrt[i] = rsqrtf((float)tot + 1.0f);
    }
    __shared__ int sh[256];
    sh[t] = tot;
    __syncthreads();
    for (int off = 1; off < 256; off <<= 1) {
        int u = (t >= off) ? sh[t - off] : 0;
        __syncthreads();
        sh[t] += u;
        __syncthreads();
    }
    if (i < N_NODES) excl[i] = sh[t] - tot;
    if (t == 255) partials[blockIdx.x] = sh[t];
}

// stages 2+3: every block redundantly scans the 196 partials, applies its
// offset -> rowptr, and folds rowptr into the chunk bases (fill = 1 gather).
__global__ __launch_bounds__(256) void k_scan23(const int* __restrict__ excl,
                                                const int* __restrict__ partials,
                                                int* __restrict__ rowptr,
                                                int* __restrict__ deg8) {
    const int t = threadIdx.x;
    int v = (t < SCAN_NB) ? partials[t] : 0;
    __shared__ int sh[256];
    __shared__ int base_s;
    sh[t] = v;
    __syncthreads();
    for (int off = 1; off < 256; off <<= 1) {
        int u = (t >= off) ? sh[t - off] : 0;
        __syncthreads();
        sh[t] += u;
        __syncthreads();
    }
    if (t == blockIdx.x) base_s = sh[t] - v;
    __syncthreads();
    const int i = blockIdx.x * 256 + t;
    if (i < N_NODES) {
        int r = excl[i] + base_s;
        rowptr[i] = r;
#pragma unroll
        for (int c = 0; c < NCHUNK; c++) deg8[c * NP + i] += r;   // slot base
    }
    if (i == 0) rowptr[N_NODES] = N_EDGES;
}

// ---------------------------------------------------------------------------
// CSR fill, atomic-free: pos = slotbase[chunk][dst] + rank
// ---------------------------------------------------------------------------
__global__ __launch_bounds__(256) void k_fill(const int* __restrict__ ei,
                                              const int* __restrict__ rank,
                                              const int* __restrict__ deg8,
                                              int* __restrict__ esrc) {
    int e0 = (blockIdx.x * 256 + threadIdx.x) * 4;
    if (e0 >= N_EDGES) return;
    const int* sb = deg8 + (e0 >> 17) * NP;
    int4 s4 = *(const int4*)&ei[e0];
    int4 d4 = *(const int4*)&ei[N_EDGES + e0];
    int4 r4 = *(const int4*)&rank[e0];
    int p0 = sb[d4.x] + r4.x;
    int p1 = sb[d4.y] + r4.y;
    int p2 = sb[d4.z] + r4.z;
    int p3 = sb[d4.w] + r4.w;
    esrc[p0] = s4.x;
    esrc[p1] = s4.y;
    esrc[p2] = s4.z;
    esrc[p3] = s4.w;
}

// ---------------------------------------------------------------------------
// CSR gather-aggregate from bf16 H, fp32 accumulate, 4-wide edge unroll,
// 16 B/lane (uint4 = 8 bf16). coef = inv_sqrt[s] * inv_sqrt[node] on the fly.
// ---------------------------------------------------------------------------
template <int F, bool OUTBF>
__global__ __launch_bounds__(256) void k_agg(const int* __restrict__ rowptr,
                                             const int* __restrict__ esrc,
                                             const float* __restrict__ inv_sqrt,
                                             const unsigned short* __restrict__ H,
                                             const float* __restrict__ bias,
                                             void* __restrict__ OUT) {
    constexpr int LPN = F / 8;              // lanes per node (16 or 8), uint4 each
    constexpr int NPB = 256 / LPN;          // nodes per block (16 or 32)
    const int t = threadIdx.x;
    const int node = blockIdx.x * NPB + t / LPN;
    const int lane = t % LPN;
    if (node >= N_NODES) return;

    const uint4* __restrict__ Hv = (const uint4*)H;   // 8 bf16 per uint4
    const int beg = rowptr[node];
    const int end = rowptr[node + 1];
    const float rsn = inv_sqrt[node];

    float acc[8];
#pragma unroll
    for (int i = 0; i < 8; i++) acc[i] = 0.f;

#define ACC8(P, C)                                                     \
    acc[0] = fmaf(blo((P).x), (C), acc[0]);                            \
    acc[1] = fmaf(bhi((P).x), (C), acc[1]);                            \
    acc[2] = fmaf(blo((P).y), (C), acc[2]);                            \
    acc[3] = fmaf(bhi((P).y), (C), acc[3]);                            \
    acc[4] = fmaf(blo((P).z), (C), acc[4]);                            \
    acc[5] = fmaf(bhi((P).z), (C), acc[5]);                            \
    acc[6] = fmaf(blo((P).w), (C), acc[6]);                            \
    acc[7] = fmaf(bhi((P).w), (C), acc[7]);

    int j = beg;
    for (; j + 3 < end; j += 4) {
        int s0 = esrc[j], s1 = esrc[j + 1], s2 = esrc[j + 2], s3 = esrc[j + 3];
        uint4 p0 = Hv[(size_t)s0 * LPN + lane];
        uint4 p1 = Hv[(size_t)s1 * LPN + lane];
        uint4 p2 = Hv[(size_t)s2 * LPN + lane];
        uint4 p3 = Hv[(size_t)s3 * LPN + lane];
        float c0 = inv_sqrt[s0] * rsn, c1 = inv_sqrt[s1] * rsn;
        float c2 = inv_sqrt[s2] * rsn, c3 = inv_sqrt[s3] * rsn;
        ACC8(p0, c0) ACC8(p1, c1) ACC8(p2, c2) ACC8(p3, c3)
    }
    for (; j < end; j++) {
        int s0 = esrc[j];
        float c0 = inv_sqrt[s0] * rsn;
        uint4 p0 = Hv[(size_t)s0 * LPN + lane];
        ACC8(p0, c0)
    }
#undef ACC8

    // self-loop + bias (self coef = rsn^2)
    uint4 ps = Hv[(size_t)node * LPN + lane];
    float idv = rsn * rsn;
    float4 b0 = ((const float4*)bias)[lane * 2];
    float4 b1 = ((const float4*)bias)[lane * 2 + 1];
    acc[0] = fmaf(blo(ps.x), idv, acc[0]) + b0.x;
    acc[1] = fmaf(bhi(ps.x), idv, acc[1]) + b0.y;
    acc[2] = fmaf(blo(ps.y), idv, acc[2]) + b0.z;
    acc[3] = fmaf(bhi(ps.y), idv, acc[3]) + b0.w;
    acc[4] = fmaf(blo(ps.z), idv, acc[4]) + b1.x;
    acc[5] = fmaf(bhi(ps.z), idv, acc[5]) + b1.y;
    acc[6] = fmaf(blo(ps.w), idv, acc[6]) + b1.z;
    acc[7] = fmaf(bhi(ps.w), idv, acc[7]) + b1.w;

    if (OUTBF) {
        uint4 pk;
        pk.x = (unsigned)f2bf(acc[0]) | ((unsigned)f2bf(acc[1]) << 16);
        pk.y = (unsigned)f2bf(acc[2]) | ((unsigned)f2bf(acc[3]) << 16);
        pk.z = (unsigned)f2bf(acc[4]) | ((unsigned)f2bf(acc[5]) << 16);
        pk.w = (unsigned)f2bf(acc[6]) | ((unsigned)f2bf(acc[7]) << 16);
        ((uint4*)OUT)[(size_t)node * LPN + lane] = pk;
    } else {
        float4* o = (float4*)OUT + ((size_t)node * LPN + lane) * 2;
        o[0] = make_float4(acc[0], acc[1], acc[2], acc[3]);
        o[1] = make_float4(acc[4], acc[5], acc[6], acc[7]);
    }
}

// ---------------------------------------------------------------------------
// column stats over bf16 A[N,128]
// ---------------------------------------------------------------------------
__global__ __launch_bounds__(256) void k_stats(const unsigned short* __restrict__ A,
                                               float* __restrict__ stats) {
    const int t  = threadIdx.x;
    const int c4 = t & 31;
    const int rr = t >> 5;
    float4 sum = make_float4(0.f, 0.f, 0.f, 0.f);
    float4 sq  = make_float4(0.f, 0.f, 0.f, 0.f);
    for (int row = blockIdx.x * 8 + rr; row < N_NODES; row += gridDim.x * 8) {
        uint2 p = *(const uint2*)&A[(size_t)row * 128 + c4 * 4];
        float vx = blo(p.x), vy = bhi(p.x), vz = blo(p.y), vw = bhi(p.y);
        sum.x += vx; sum.y += vy; sum.z += vz; sum.w += vw;
        sq.x += vx * vx; sq.y += vy * vy; sq.z += vz * vz; sq.w += vw * vw;
    }
    __shared__ float4 red[2][8][32];
    red[0][rr][c4] = sum;
    red[1][rr][c4] = sq;
    __syncthreads();
    if (t < 32) {
        float4 s = make_float4(0.f, 0.f, 0.f, 0.f);
        float4 q = make_float4(0.f, 0.f, 0.f, 0.f);
#pragma unroll
        for (int i = 0; i < 8; i++) {
            float4 a = red[0][i][t];
            float4 b = red[1][i][t];
            s.x += a.x; s.y += a.y; s.z += a.z; s.w += a.w;
            q.x += b.x; q.y += b.y; q.z += b.z; q.w += b.w;
        }
        int c = t * 4;
        atomicAdd(&stats[c + 0], s.x); atomicAdd(&stats[c + 1], s.y);
        atomicAdd(&stats[c + 2], s.z); atomicAdd(&stats[c + 3], s.w);
        atomicAdd(&stats[128 + c + 0], q.x); atomicAdd(&stats[128 + c + 1], q.y);
        atomicAdd(&stats[128 + c + 2], q.z); atomicAdd(&stats[128 + c + 3], q.w);
    }
}

// ---------------------------------------------------------------------------
extern "C" void kernel_launch(void* const* d_in, const int* in_sizes, int n_in,
                              void* d_out, int out_size, void* d_ws, size_t ws_size,
                              hipStream_t stream) {
    const float* x   = (const float*)d_in[0];
    const int*   ei  = (const int*)d_in[1];
    const float* W1  = (const float*)d_in[2];
    const float* b1  = (const float*)d_in[3];
    const float* g1  = (const float*)d_in[4];
    const float* bt1 = (const float*)d_in[5];
    const float* W2  = (const float*)d_in[6];
    const float* b2  = (const float*)d_in[7];
    const float* g2  = (const float*)d_in[8];
    const float* bt2 = (const float*)d_in[9];
    const float* W3  = (const float*)d_in[10];
    const float* b3  = (const float*)d_in[11];
    float* out = (float*)d_out;                 // [N, 64] fp32

    char* ws = (char*)d_ws;
    size_t off = 0;
    auto alloc = [&](size_t bytes) { char* p = ws + off; off += (bytes + 255) & ~(size_t)255; return p; };
    // contiguous zero-init region: deg8 | stats1 | stats2 (single memset)
    int*   deg8     = (int*)  alloc((size_t)NCHUNK * NP * 4);
    float* stats1   = (float*)alloc(256 * 4);
    float* stats2   = (float*)alloc(256 * 4);
    const size_t zbytes = (size_t)((char*)(stats2 + 256) - (char*)deg8);
    float* inv_sqrt = (float*)alloc((size_t)N_NODES * 4);
    int*   excl     = (int*)  alloc((size_t)N_NODES * 4);
    int*   partials = (int*)  alloc(256 * 4);
    int*   rowptr   = (int*)  alloc((size_t)(N_NODES + 1) * 4);
    int*   rank     = (int*)  alloc((size_t)N_EDGES * 4);
    int*   esrc     = (int*)  alloc((size_t)N_EDGES * 4);
    unsigned short* Wf1 = (unsigned short*)alloc((size_t)128 * 128 * 2);
    unsigned short* Wf2 = (unsigned short*)alloc((size_t)128 * 128 * 2);
    unsigned short* Wf3 = (unsigned short*)alloc((size_t)64 * 128 * 2);
    unsigned short* h1  = (unsigned short*)alloc((size_t)N_NODES * 128 * 2);
    unsigned short* h2  = (unsigned short*)alloc((size_t)N_NODES * 128 * 2);
    unsigned short* h3  = (unsigned short*)alloc((size_t)N_NODES * 64 * 2);
    unsigned short* agg1 = (unsigned short*)alloc((size_t)N_NODES * 128 * 2);
    unsigned short* agg2 = (unsigned short*)alloc((size_t)N_NODES * 128 * 2);

    hipMemsetAsync(deg8, 0, zbytes, stream);

    // weights packed first (tiny) so the fused kernel can use Wf1
    k_wconv_all<<<160, 256, 0, stream>>>(W1, W2, W3, Wf1, Wf2, Wf3);

    // chunked histogram+rank (atomic pipe) || layer-1 GEMM (MFMA pipe)
    k_prep_gemm1<<<FILL_NB + GEMM_NB, 256, 0, stream>>>(ei, deg8, rank, x, Wf1, h1);

    k_scan1<<<SCAN_NB, 256, 0, stream>>>(deg8, inv_sqrt, excl, partials);
    k_scan23<<<SCAN_NB, 256, 0, stream>>>(excl, partials, rowptr, deg8);
    k_fill<<<FILL_NB, 256, 0, stream>>>(ei, rank, deg8, esrc);

    // layer 1 aggregate
    k_agg<128, true><<<N_NODES / 16, 256, 0, stream>>>(rowptr, esrc, inv_sqrt, h1, b1, agg1);
    k_stats<<<256, 256, 0, stream>>>(agg1, stats1);

    // layer 2
    k_gemm_bn<128><<<GEMM_NB, 256, 0, stream>>>(agg1, Wf2, stats1, g1, bt1, h2);
    k_agg<128, true><<<N_NODES / 16, 256, 0, stream>>>(rowptr, esrc, inv_sqrt, h2, b2, agg2);
    k_stats<<<256, 256, 0, stream>>>(agg2, stats2);

    // layer 3 (aggregate straight into d_out, fp32)
    k_gemm_bn<64><<<GEMM_NB, 256, 0, stream>>>(agg2, Wf3, stats2, g2, bt2, h3);
    k_agg<64, false><<<(N_NODES + 31) / 32, 256, 0, stream>>>(rowptr, esrc, inv_sqrt, h3, b3, out);
}